// Round 10
// baseline (705.366 us; speedup 1.0000x reference)
//
#include <hip/hip_runtime.h>
#include <stdint.h>

typedef __bf16 bf16;
typedef __bf16 bf16x8 __attribute__((ext_vector_type(8)));
typedef float  f32x4  __attribute__((ext_vector_type(4)));

#define MFMA16(a, b, c) __builtin_amdgcn_mfma_f32_16x16x32_bf16((a), (b), (c), 0, 0, 0)

static constexpr int    Bn = 4, Tn = 2048, Cn = 2048, HD = 128;
static constexpr size_t TEN = (size_t)Bn * Tn * Cn;   // 16,777,216 elems

__device__ __forceinline__ void gld16(const void* g, void* l) {
  __builtin_amdgcn_global_load_lds(
      (const __attribute__((address_space(1))) void*)g,
      (__attribute__((address_space(3))) void*)l, 16, 0, 0);
}

// ---------------------------------------------------------------------------
// f32 -> bf16 conversion, 8 elems/thread (x tensor)
// ---------------------------------------------------------------------------
__global__ __launch_bounds__(256) void to_bf16(const float* __restrict__ src,
                                               bf16* __restrict__ dst) {
  const size_t i = ((size_t)blockIdx.x * 256 + threadIdx.x) * 8;
  float4 a = *(const float4*)(src + i);
  float4 b = *(const float4*)(src + i + 4);
  bf16x8 o = {(bf16)a.x, (bf16)a.y, (bf16)a.z, (bf16)a.w,
              (bf16)b.x, (bf16)b.y, (bf16)b.z, (bf16)b.w};
  *(bf16x8*)(dst + i) = o;
}

// ---------------------------------------------------------------------------
// R9: all four weight matrices in ONE launch (blockIdx.y selects source);
// dst regions are contiguous (TEN/4 each). Saves 3 kernel launches.
// ---------------------------------------------------------------------------
__global__ __launch_bounds__(256) void to_bf16_w4(const float* __restrict__ w0,
                                                  const float* __restrict__ w1,
                                                  const float* __restrict__ w2,
                                                  const float* __restrict__ w3,
                                                  bf16* __restrict__ dst) {
  const int s = blockIdx.y;
  const float* src = (s == 0) ? w0 : (s == 1) ? w1 : (s == 2) ? w2 : w3;
  bf16* d = dst + (size_t)s * (TEN / 4);
  const size_t i = ((size_t)blockIdx.x * 256 + threadIdx.x) * 8;
  float4 a = *(const float4*)(src + i);
  float4 b = *(const float4*)(src + i + 4);
  bf16x8 o = {(bf16)a.x, (bf16)a.y, (bf16)a.z, (bf16)a.w,
              (bf16)b.x, (bf16)b.y, (bf16)b.z, (bf16)b.w};
  *(bf16x8*)(d + i) = o;
}

// ---------------------------------------------------------------------------
// RoPE cos/sin table: tbl[t*64 + i] = {cos(t*f_i), sin(t*f_i)}, 2048x64.
// ---------------------------------------------------------------------------
__global__ __launch_bounds__(256) void rope_table(float2* __restrict__ tbl) {
  const int idx = blockIdx.x * 256 + threadIdx.x;   // 512 blocks -> 131072
  const int t = idx >> 6, i = idx & 63;
  const float ang = (float)t * __expf(-(float)i * 0.14391156831212787f); // ln(1e4)/64
  float s, c;
  sincosf(ang, &s, &c);
  tbl[idx] = make_float2(c, s);
}

// ---------------------------------------------------------------------------
// Pipelined 256x256 GEMM core -- R5 version restored VERBATIM (measured
// 257.0 us; R8's barrier sandwich regressed to 269.4 and is abandoned).
// BK=64, 512 threads (8 waves = 2M x 4N), per-wave C = 128x64.
// LDS: 2 dbuf x (A,B) x [2 K-halves][256][32] = 128 KB. 4 phases per K-tile;
// counted vmcnt(4) + raw s_barrier at end of ph1/ph3 only.
//
// T2 LDS swizzle: physical 16B slot = logical ^ ((row>>1)&3); applied via
// pre-swizzled global source slot ((tid&3)^((tid>>3)&3)) + XOR'd read addr
// (quad ^ ((l16>>1)&3)). Verified R3: fragment reads conflict-free.
//
// Wait ledger (per thread, 2 gld16 per phase):
//   stage order iter t: ph0 A-k0(t+1), ph1 B-k0(t+1), ph2 A-k1(t+1), ph3 B-k1(t+1)
//   end-ph3 wait vmcnt(4): outstanding allowed = {A-k1,B-k1}(t+1);
//     guarantees {A-k0,B-k0}(t+1) landed -> read at iter t+1 ph0/ph1.  OK
//   end-ph1 (iter t+1) wait vmcnt(4): outstanding = {A-k0,B-k0}(t+2);
//     guarantees {A-k1,B-k1}(t+1) landed -> read at iter t+1 ph2/ph3.  OK
//   Buffer reuse: writes for tile t+2 (buf p) are issued only after the
//     end-ph3 barrier of iter t, by which point all reads of tile t (buf p)
//     have completed.                                                   OK
// ---------------------------------------------------------------------------
__device__ __forceinline__ void gemm_core256(const bf16* __restrict__ A,
                                             const bf16* __restrict__ Bt,
                                             int m0, int n0, int K,
                                             f32x4 (&acc)[8][4],
                                             bf16* sA, bf16* sB) {
  const int tid  = threadIdx.x;
  const int lane = tid & 63, wid = tid >> 6;
  const int quad = lane >> 4, l16 = lane & 15;
  const int wm = (wid >> 2) * 128, wn = (wid & 3) * 64;

  const int srow = tid >> 2;
  const int scol = ((tid & 3) ^ ((tid >> 3) & 3)) * 8;   // T2 pre-swizzled source
  const bf16* gA = A + (size_t)(m0 + srow) * K + scol;
  const bf16* gB = Bt + (size_t)(n0 + srow) * K + scol;
  const int HALF = 8192;                    // elems per K-half (256 x 32)
  const int sOff = srow * 32 + (tid & 3) * 8;            // linear LDS dest
  const size_t rs = (size_t)128 * K;        // +128 rows in global

  const int xsl = ((l16 >> 1) & 3);
  const int rofA = (quad ^ xsl) * 8;        // elem offset of this lane's slot

  // prologue: tile 0, all four halves, full drain once
  gld16(gA,           sA + sOff);        gld16(gA + rs,       sA + sOff + 4096);
  gld16(gB,           sB + sOff);        gld16(gB + rs,       sB + sOff + 4096);
  gld16(gA + 32,      sA + HALF + sOff); gld16(gA + 32 + rs,  sA + HALF + sOff + 4096);
  gld16(gB + 32,      sB + HALF + sOff); gld16(gB + 32 + rs,  sB + HALF + sOff + 4096);
  asm volatile("s_waitcnt vmcnt(0)" ::: "memory");
  __builtin_amdgcn_s_barrier();
  __builtin_amdgcn_sched_barrier(0);

  const int nt = K >> 6;
  int p = 0;
  for (int t = 0; t < nt; ++t, p ^= 1) {
    const bf16* aT = sA + p * (2 * HALF);
    const bf16* bT = sB + p * (2 * HALF);
    bf16* aN = sA + (p ^ 1) * (2 * HALF);
    bf16* bN = sB + (p ^ 1) * (2 * HALF);
    const bool pf = (t + 1 < nt);
    const size_t g0 = (size_t)(t + 1) * 64;

    bf16x8 af[8], bfr[4];
    // ---------------- phase 0: ks=0, in 0..1; stage A-k0(t+1) ----------------
#pragma unroll
    for (int im = 0; im < 8; im++)
      af[im] = *(const bf16x8*)&aT[(wm + im * 16 + l16) * 32 + rofA];
    bfr[0] = *(const bf16x8*)&bT[(wn +  0 + l16) * 32 + rofA];
    bfr[1] = *(const bf16x8*)&bT[(wn + 16 + l16) * 32 + rofA];
    if (pf) { gld16(gA + g0, aN + sOff); gld16(gA + g0 + rs, aN + sOff + 4096); }
    __builtin_amdgcn_s_setprio(1);
#pragma unroll
    for (int im = 0; im < 8; im++) {
      acc[im][0] = MFMA16(af[im], bfr[0], acc[im][0]);
      acc[im][1] = MFMA16(af[im], bfr[1], acc[im][1]);
    }
    __builtin_amdgcn_s_setprio(0);
    // ---------------- phase 1: ks=0, in 2..3; stage B-k0(t+1) ----------------
    bfr[2] = *(const bf16x8*)&bT[(wn + 32 + l16) * 32 + rofA];
    bfr[3] = *(const bf16x8*)&bT[(wn + 48 + l16) * 32 + rofA];
    if (pf) { gld16(gB + g0, bN + sOff); gld16(gB + g0 + rs, bN + sOff + 4096); }
    __builtin_amdgcn_s_setprio(1);
#pragma unroll
    for (int im = 0; im < 8; im++) {
      acc[im][2] = MFMA16(af[im], bfr[2], acc[im][2]);
      acc[im][3] = MFMA16(af[im], bfr[3], acc[im][3]);
    }
    __builtin_amdgcn_s_setprio(0);
    asm volatile("s_waitcnt vmcnt(4)" ::: "memory");
    __builtin_amdgcn_s_barrier();
    __builtin_amdgcn_sched_barrier(0);
    // ---------------- phase 2: ks=1, in 0..1; stage A-k1(t+1) ----------------
#pragma unroll
    for (int im = 0; im < 8; im++)
      af[im] = *(const bf16x8*)&aT[HALF + (wm + im * 16 + l16) * 32 + rofA];
    bfr[0] = *(const bf16x8*)&bT[HALF + (wn +  0 + l16) * 32 + rofA];
    bfr[1] = *(const bf16x8*)&bT[HALF + (wn + 16 + l16) * 32 + rofA];
    if (pf) { gld16(gA + g0 + 32, aN + HALF + sOff);
              gld16(gA + g0 + 32 + rs, aN + HALF + sOff + 4096); }
    __builtin_amdgcn_s_setprio(1);
#pragma unroll
    for (int im = 0; im < 8; im++) {
      acc[im][0] = MFMA16(af[im], bfr[0], acc[im][0]);
      acc[im][1] = MFMA16(af[im], bfr[1], acc[im][1]);
    }
    __builtin_amdgcn_s_setprio(0);
    // ---------------- phase 3: ks=1, in 2..3; stage B-k1(t+1) ----------------
    bfr[2] = *(const bf16x8*)&bT[HALF + (wn + 32 + l16) * 32 + rofA];
    bfr[3] = *(const bf16x8*)&bT[HALF + (wn + 48 + l16) * 32 + rofA];
    if (pf) { gld16(gB + g0 + 32, bN + HALF + sOff);
              gld16(gB + g0 + 32 + rs, bN + HALF + sOff + 4096); }
    __builtin_amdgcn_s_setprio(1);
#pragma unroll
    for (int im = 0; im < 8; im++) {
      acc[im][2] = MFMA16(af[im], bfr[2], acc[im][2]);
      acc[im][3] = MFMA16(af[im], bfr[3], acc[im][3]);
    }
    __builtin_amdgcn_s_setprio(0);
    asm volatile("s_waitcnt vmcnt(4)" ::: "memory");
    __builtin_amdgcn_s_barrier();
    __builtin_amdgcn_sched_barrier(0);
  }
}

// ---------------------------------------------------------------------------
// QKV GEMM (256x256 tiles) with fused epilogues (R5 mapping):
//   sel 0 (q): RoPE + scale*log2e fold; sel 1 (k): RoPE; sel 2 (v): transpose.
// ---------------------------------------------------------------------------
__global__ __launch_bounds__(512, 2) void qkv_gemm(const bf16* __restrict__ X,
                                                   const bf16* __restrict__ Wq,
                                                   const bf16* __restrict__ Wk,
                                                   const bf16* __restrict__ Wv,
                                                   bf16* __restrict__ q,
                                                   bf16* __restrict__ kk,
                                                   bf16* __restrict__ vt,
                                                   const float2* __restrict__ tbl) {
  __shared__ bf16 lds[65536];              // 128 KB
  const int sel = blockIdx.x >> 3;
  const int n0 = (blockIdx.x & 7) * 256;
  const int m0 = blockIdx.y * 256;
  const bf16* Bt = (sel == 0) ? Wq : (sel == 1) ? Wk : Wv;

  f32x4 acc[8][4] = {};
  gemm_core256(X, Bt, m0, n0, Cn, acc, lds, lds + 32768);

  const int tid  = threadIdx.x;
  const int lane = tid & 63, wid = tid >> 6;
  const int quad = lane >> 4, l16 = lane & 15;
  const int wm = (wid >> 2) * 128, wn = (wid & 3) * 64;

  if (sel < 2) {
    // ---- RoPE epilogue: pair (2i,2i+1) is adjacent cols -> lane^1 ----
    bf16* out = (sel == 0) ? q : kk;
    const float mscale =
        (sel == 0) ? (0.08838834764831845f * 1.4426950408889634f) : 1.0f;
#pragma unroll
    for (int im = 0; im < 8; im++)
#pragma unroll
      for (int in = 0; in < 4; in++) {
        const int col = n0 + wn + in * 16 + l16;
        const int fi  = (col & 127) >> 1;
        const bool even = ((col & 1) == 0);
#pragma unroll
        for (int r = 0; r < 4; r++) {
          const int row = m0 + wm + im * 16 + quad * 4 + r;
          const int t   = row & (Tn - 1);
          const float xv = acc[im][in][r];
          const float xp = __shfl_xor(xv, 1);
          const float2 cs = tbl[(size_t)t * 64 + fi];
          const float o = even ? (xv * cs.x - xp * cs.y)
                               : (xv * cs.x + xp * cs.y);
          out[(size_t)row * Cn + col] = (bf16)(o * mscale);
        }
      }
  } else {
    // ---- V transpose epilogue: two 128-col halves through LDS ----
    bf16* tr = lds;                         // 256 x 136 = 69.6 KB (<=128 KB)
    const int b  = m0 >> 11;                // 256 | 2048 -> tile never spans b
    const int t0 = m0 & (Tn - 1);
#pragma unroll
    for (int h = 0; h < 2; h++) {
      __syncthreads();
      if (((wid >> 1) & 1) == h) {          // waves whose wn lies in this half
        const int cb = (wid & 1) * 64;
#pragma unroll
        for (int im = 0; im < 8; im++)
#pragma unroll
          for (int in = 0; in < 4; in++)
#pragma unroll
            for (int r = 0; r < 4; r++)
              tr[(wm + im * 16 + quad * 4 + r) * 136 + cb + in * 16 + l16] =
                  (bf16)acc[im][in][r];
      }
      __syncthreads();
      bf16* dst = vt + ((size_t)(b * Cn + n0 + h * 128)) * Tn + t0;
#pragma unroll
      for (int j = 0; j < 8; j++) {
        const int lin = j * 512 + tid;      // 128 c-rows x 32 t-octets
        const int c  = lin >> 5;
        const int t8 = (lin & 31) * 8;
        bf16x8 o;
#pragma unroll
        for (int e = 0; e < 8; e++) o[e] = tr[(t8 + e) * 136 + c];
        *(bf16x8*)(dst + (size_t)c * Tn + t8) = o;
      }
    }
  }
}

// ---------------------------------------------------------------------------
// Output projection GEMM (256x256 tiles, f32 out). R5 mapping.
// ---------------------------------------------------------------------------
__global__ __launch_bounds__(512, 2) void out_gemm(const bf16* __restrict__ Y,
                                                   const bf16* __restrict__ Wp,
                                                   float* __restrict__ O) {
  __shared__ bf16 lds[65536];
  const int m0 = blockIdx.y * 256, n0 = blockIdx.x * 256;

  f32x4 acc[8][4] = {};
  gemm_core256(Y, Wp, m0, n0, Cn, acc, lds, lds + 32768);

  const int tid  = threadIdx.x;
  const int lane = tid & 63, wid = tid >> 6;
  const int quad = lane >> 4, l16 = lane & 15;
  const int wm = (wid >> 2) * 128, wn = (wid & 3) * 64;
#pragma unroll
  for (int im = 0; im < 8; im++)
#pragma unroll
    for (int in = 0; in < 4; in++)
#pragma unroll
      for (int r = 0; r < 4; r++) {
        const int row = m0 + wm + im * 16 + quad * 4 + r;
        const int col = n0 + wn + in * 16 + l16;
        O[(size_t)row * Cn + col] = acc[im][in][r];
      }
}

// ---------------------------------------------------------------------------
// Causal flash attention: R5 structure (128 q-rows, 4 waves, LDS-staged K/V,
// defer-max + ones-MFMA row-sum) + R9 T14 async-STAGE split:
//   loop: {ds_write regs(kt) -> barrier -> ISSUE loads(kt+1) -> compute(kt)
//          -> barrier}. The global-load latency (~200-900 cy), previously
//   exposed serially before every tile's barrier, now hides under the
//   ~2000-cy compute phase. +32 VGPR (8 uint4 in flight), still 2 blocks/CU.
// ---------------------------------------------------------------------------
__global__ __launch_bounds__(256, 2) void attn(const bf16* __restrict__ q,
                                               const bf16* __restrict__ k,
                                               const bf16* __restrict__ vt,
                                               bf16* __restrict__ y) {
  __shared__ bf16 sK[64 * 136];    // K tile (64 keys x 128 d), stride 136
  __shared__ bf16 sVt[128 * 72];   // V^T tile (128 d x 64 keys), stride 72
  __shared__ bf16 sP[128 * 72];    // P tile (128 q x 64 keys), stride 72

  const int tid = threadIdx.x;
  const int bh = blockIdx.x;
  const int qt = 15 - blockIdx.y;          // heavy blocks first
  const int b = bh >> 4, h = bh & 15;
  const int q0 = qt * 128;
  const int lane = tid & 63, w = tid >> 6;
  const int quad = lane >> 4, l16 = lane & 15;

  const bf16* qbase  = q + ((size_t)(b * Tn + q0)) * Cn + h * HD;
  const bf16* kbase  = k + ((size_t)(b * Tn)) * Cn + h * HD;
  const bf16* vtbase = vt + ((size_t)(b * Cn + h * HD)) * Tn;

  // staging geometry: 1024 16B-chunks per tile, 256 threads x 4
  int krow[4], kc8[4], vrow[4], vk8[4];
#pragma unroll
  for (int i = 0; i < 4; i++) {
    const int lin = i * 256 + tid;
    krow[i] = lin >> 4; kc8[i] = (lin & 15) * 8;
    vrow[i] = lin >> 3; vk8[i] = (lin & 7) * 8;
  }

  bf16x8 qf[2][4];
#pragma unroll
  for (int im = 0; im < 2; im++)
#pragma unroll
    for (int s = 0; s < 4; s++)
      qf[im][s] = *(const bf16x8*)(qbase +
          (size_t)(w * 32 + im * 16 + l16) * Cn + s * 32 + quad * 8);

  f32x4 O[2][8] = {};
  f32x4 lacc[2] = {};
  float mrow[2][4];
#pragma unroll
  for (int im = 0; im < 2; im++)
#pragma unroll
    for (int r = 0; r < 4; r++) mrow[im][r] = -1e30f;

  const bf16x8 vone = {(bf16)1.f, (bf16)1.f, (bf16)1.f, (bf16)1.f,
                       (bf16)1.f, (bf16)1.f, (bf16)1.f, (bf16)1.f};

  // T14 prologue: load tile 0 into registers
  uint4 kreg[4], vreg[4];
#pragma unroll
  for (int i = 0; i < 4; i++) {
    kreg[i] = *(const uint4*)(kbase + (size_t)krow[i] * Cn + kc8[i]);
    vreg[i] = *(const uint4*)(vtbase + (size_t)vrow[i] * Tn + vk8[i]);
  }

  const int nkt = 2 * qt + 2;
  for (int kt = 0; kt < nkt; kt++) {
    // write staged regs -> LDS (loads issued >= 1 compute-phase ago: wait ~free)
#pragma unroll
    for (int i = 0; i < 4; i++) {
      *(uint4*)&sK[krow[i] * 136 + kc8[i]] = kreg[i];
      *(uint4*)&sVt[vrow[i] * 72 + vk8[i]] = vreg[i];
    }
    __syncthreads();

    // T14: issue next tile's loads now; latency hides under compute below
    if (kt + 1 < nkt) {
#pragma unroll
      for (int i = 0; i < 4; i++) {
        kreg[i] = *(const uint4*)(kbase +
            (size_t)((kt + 1) * 64 + krow[i]) * Cn + kc8[i]);
        vreg[i] = *(const uint4*)(vtbase +
            (size_t)vrow[i] * Tn + (kt + 1) * 64 + vk8[i]);
      }
    }

    if (kt * 64 <= q0 + w * 32 + 31) {
      f32x4 sv[2][4] = {};
      __builtin_amdgcn_s_setprio(1);
#pragma unroll
      for (int s = 0; s < 4; s++)
#pragma unroll
        for (int jn = 0; jn < 4; jn++) {
          bf16x8 kf = *(const bf16x8*)&sK[(jn * 16 + l16) * 136 + s * 32 + quad * 8];
          sv[0][jn] = MFMA16(qf[0][s], kf, sv[0][jn]);
          sv[1][jn] = MFMA16(qf[1][s], kf, sv[1][jn]);
        }
      __builtin_amdgcn_s_setprio(0);

      const bool anymask = (kt >= 2 * qt);
#pragma unroll
      for (int im = 0; im < 2; im++)
#pragma unroll
        for (int r = 0; r < 4; r++) {
          float pv[4];
          float mx = -1e30f;
#pragma unroll
          for (int jn = 0; jn < 4; jn++) {
            float x = sv[im][jn][r];
            if (anymask) {
              int key = kt * 64 + jn * 16 + l16;
              int qr  = q0 + w * 32 + im * 16 + quad * 4 + r;
              if (key > qr) x = -1e30f;
            }
            pv[jn] = x;
            mx = fmaxf(mx, x);
          }
          mx = fmaxf(mx, __shfl_xor(mx, 1));
          mx = fmaxf(mx, __shfl_xor(mx, 2));
          mx = fmaxf(mx, __shfl_xor(mx, 4));
          mx = fmaxf(mx, __shfl_xor(mx, 8));
          // T13 defer-max: rescale only when some row grew past mrow + 8
          if (__any(mx > mrow[im][r] + 8.0f)) {
            const float mn = fmaxf(mrow[im][r], mx);
            const float alpha = exp2f(mrow[im][r] - mn);
            mrow[im][r] = mn;
#pragma unroll
            for (int n = 0; n < 8; n++) O[im][n][r] *= alpha;
            lacc[im][r] *= alpha;
          }
          const float mref = mrow[im][r];
#pragma unroll
          for (int jn = 0; jn < 4; jn++) {
            float e = exp2f(pv[jn] - mref);
            sP[(w * 32 + im * 16 + quad * 4 + r) * 72 + jn * 16 + l16] = (bf16)e;
          }
        }

      __builtin_amdgcn_s_setprio(1);
#pragma unroll
      for (int s2 = 0; s2 < 2; s2++) {
        bf16x8 pf0 = *(const bf16x8*)&sP[(w * 32 + l16) * 72 + s2 * 32 + quad * 8];
        bf16x8 pf1 = *(const bf16x8*)&sP[(w * 32 + 16 + l16) * 72 + s2 * 32 + quad * 8];
#pragma unroll
        for (int n = 0; n < 8; n++) {
          bf16x8 vf = *(const bf16x8*)&sVt[(n * 16 + l16) * 72 + s2 * 32 + quad * 8];
          O[0][n] = MFMA16(pf0, vf, O[0][n]);
          O[1][n] = MFMA16(pf1, vf, O[1][n]);
        }
        lacc[0] = MFMA16(pf0, vone, lacc[0]);   // row-sum l += P . 1
        lacc[1] = MFMA16(pf1, vone, lacc[1]);
      }
      __builtin_amdgcn_s_setprio(0);
    }
    __syncthreads();
  }

#pragma unroll
  for (int im = 0; im < 2; im++) {
    bf16* ybase = y + ((size_t)(b * Tn + q0 + w * 32 + im * 16)) * Cn + h * HD;
#pragma unroll
    for (int r = 0; r < 4; r++) {
      const float inv = 1.f / lacc[im][r];
#pragma unroll
      for (int n = 0; n < 8; n++)
        ybase[(size_t)(quad * 4 + r) * Cn + n * 16 + l16] = (bf16)(O[im][n][r] * inv);
    }
  }
}

// ---------------------------------------------------------------------------
// Workspace layout (bf16 elems):
//   [0,TEN)       q          (B*T, C)   roped+scaled
//   [TEN,2TEN)    k          (B*T, C)   roped
//   [2TEN,3TEN)   vt         (B, C, T)
//   [3TEN,4TEN)   xb | y     (xb dead after qkv_gemm; y written by attn)
//   [4TEN,5TEN)   wqb wkb wvb wpb (TEN/4 each, contiguous)
//   [5TEN, +1MB)  rope table (float2, 2048x64)
// ---------------------------------------------------------------------------
extern "C" void kernel_launch(void* const* d_in, const int* in_sizes, int n_in,
                              void* d_out, int out_size, void* d_ws, size_t ws_size,
                              hipStream_t stream) {
  (void)in_sizes; (void)n_in; (void)out_size; (void)ws_size;
  const float* x  = (const float*)d_in[0];
  const float* Wq = (const float*)d_in[1];
  const float* Wk = (const float*)d_in[2];
  const float* Wv = (const float*)d_in[3];
  const float* Wp = (const float*)d_in[4];
  float* out = (float*)d_out;
  bf16*  ws  = (bf16*)d_ws;

  bf16* q   = ws;
  bf16* kk  = ws + TEN;
  bf16* vt  = ws + 2 * TEN;
  bf16* y   = ws + 3 * TEN;
  bf16* xb  = ws + 3 * TEN;          // alias y (dead after qkv_gemm)
  bf16* wqb = ws + 4 * TEN;
  bf16* wkb = ws + 4 * TEN + TEN / 4;
  bf16* wvb = ws + 4 * TEN + TEN / 2;
  bf16* wpb = ws + 4 * TEN + 3 * (TEN / 4);
  float2* tbl = (float2*)(ws + 5 * TEN);

  rope_table <<<dim3(512),  256, 0, stream>>>(tbl);
  to_bf16    <<<dim3(8192), 256, 0, stream>>>(x, xb);
  to_bf16_w4 <<<dim3(2048, 4), 256, 0, stream>>>(Wq, Wk, Wv, Wp, wqb);
  qkv_gemm   <<<dim3(24, 32), 512, 0, stream>>>(xb, wqb, wkb, wvb, q, kk, vt, tbl);
  attn       <<<dim3(64, 16), 256, 0, stream>>>(q, kk, vt, y);
  out_gemm   <<<dim3(8, 32), 512, 0, stream>>>(y, wpb, out);
}

// Round 11
// 691.268 us; speedup vs baseline: 1.0204x; 1.0204x over previous
//
#include <hip/hip_runtime.h>
#include <stdint.h>

typedef __bf16 bf16;
typedef __bf16 bf16x8 __attribute__((ext_vector_type(8)));
typedef float  f32x4  __attribute__((ext_vector_type(4)));

#define MFMA16(a, b, c) __builtin_amdgcn_mfma_f32_16x16x32_bf16((a), (b), (c), 0, 0, 0)

static constexpr int    Bn = 4, Tn = 2048, Cn = 2048, HD = 128;
static constexpr size_t TEN = (size_t)Bn * Tn * Cn;   // 16,777,216 elems

__device__ __forceinline__ void gld16(const void* g, void* l) {
  __builtin_amdgcn_global_load_lds(
      (const __attribute__((address_space(1))) void*)g,
      (__attribute__((address_space(3))) void*)l, 16, 0, 0);
}

// ---------------------------------------------------------------------------
// f32 -> bf16 conversion, 8 elems/thread (x tensor)
// ---------------------------------------------------------------------------
__global__ __launch_bounds__(256) void to_bf16(const float* __restrict__ src,
                                               bf16* __restrict__ dst) {
  const size_t i = ((size_t)blockIdx.x * 256 + threadIdx.x) * 8;
  float4 a = *(const float4*)(src + i);
  float4 b = *(const float4*)(src + i + 4);
  bf16x8 o = {(bf16)a.x, (bf16)a.y, (bf16)a.z, (bf16)a.w,
              (bf16)b.x, (bf16)b.y, (bf16)b.z, (bf16)b.w};
  *(bf16x8*)(dst + i) = o;
}

// ---------------------------------------------------------------------------
// All four weight matrices in ONE launch (blockIdx.y selects source);
// dst regions are contiguous (TEN/4 each).
// ---------------------------------------------------------------------------
__global__ __launch_bounds__(256) void to_bf16_w4(const float* __restrict__ w0,
                                                  const float* __restrict__ w1,
                                                  const float* __restrict__ w2,
                                                  const float* __restrict__ w3,
                                                  bf16* __restrict__ dst) {
  const int s = blockIdx.y;
  const float* src = (s == 0) ? w0 : (s == 1) ? w1 : (s == 2) ? w2 : w3;
  bf16* d = dst + (size_t)s * (TEN / 4);
  const size_t i = ((size_t)blockIdx.x * 256 + threadIdx.x) * 8;
  float4 a = *(const float4*)(src + i);
  float4 b = *(const float4*)(src + i + 4);
  bf16x8 o = {(bf16)a.x, (bf16)a.y, (bf16)a.z, (bf16)a.w,
              (bf16)b.x, (bf16)b.y, (bf16)b.z, (bf16)b.w};
  *(bf16x8*)(d + i) = o;
}

// ---------------------------------------------------------------------------
// RoPE cos/sin table: tbl[t*64 + i] = {cos(t*f_i), sin(t*f_i)}, 2048x64.
// ---------------------------------------------------------------------------
__global__ __launch_bounds__(256) void rope_table(float2* __restrict__ tbl) {
  const int idx = blockIdx.x * 256 + threadIdx.x;   // 512 blocks -> 131072
  const int t = idx >> 6, i = idx & 63;
  const float ang = (float)t * __expf(-(float)i * 0.14391156831212787f); // ln(1e4)/64
  float s, c;
  sincosf(ang, &s, &c);
  tbl[idx] = make_float2(c, s);
}

// ---------------------------------------------------------------------------
// Pipelined 256x256 GEMM core -- R5 version (measured 257.0 us; frozen).
// BK=64, 512 threads (8 waves = 2M x 4N), per-wave C = 128x64.
// LDS: 2 dbuf x (A,B) x [2 K-halves][256][32] = 128 KB. 4 phases per K-tile;
// counted vmcnt(4) + raw s_barrier at end of ph1/ph3 only.
//
// T2 LDS swizzle: physical 16B slot = logical ^ ((row>>1)&3); applied via
// pre-swizzled global source slot ((tid&3)^((tid>>3)&3)) + XOR'd read addr
// (quad ^ ((l16>>1)&3)). Verified R3: fragment reads conflict-free.
//
// Wait ledger (per thread, 2 gld16 per phase):
//   stage order iter t: ph0 A-k0(t+1), ph1 B-k0(t+1), ph2 A-k1(t+1), ph3 B-k1(t+1)
//   end-ph3 wait vmcnt(4): outstanding allowed = {A-k1,B-k1}(t+1);
//     guarantees {A-k0,B-k0}(t+1) landed -> read at iter t+1 ph0/ph1.  OK
//   end-ph1 (iter t+1) wait vmcnt(4): outstanding = {A-k0,B-k0}(t+2);
//     guarantees {A-k1,B-k1}(t+1) landed -> read at iter t+1 ph2/ph3.  OK
//   Buffer reuse: writes for tile t+2 (buf p) are issued only after the
//     end-ph3 barrier of iter t, by which point all reads of tile t (buf p)
//     have completed.                                                   OK
// ---------------------------------------------------------------------------
__device__ __forceinline__ void gemm_core256(const bf16* __restrict__ A,
                                             const bf16* __restrict__ Bt,
                                             int m0, int n0, int K,
                                             f32x4 (&acc)[8][4],
                                             bf16* sA, bf16* sB) {
  const int tid  = threadIdx.x;
  const int lane = tid & 63, wid = tid >> 6;
  const int quad = lane >> 4, l16 = lane & 15;
  const int wm = (wid >> 2) * 128, wn = (wid & 3) * 64;

  const int srow = tid >> 2;
  const int scol = ((tid & 3) ^ ((tid >> 3) & 3)) * 8;   // T2 pre-swizzled source
  const bf16* gA = A + (size_t)(m0 + srow) * K + scol;
  const bf16* gB = Bt + (size_t)(n0 + srow) * K + scol;
  const int HALF = 8192;                    // elems per K-half (256 x 32)
  const int sOff = srow * 32 + (tid & 3) * 8;            // linear LDS dest
  const size_t rs = (size_t)128 * K;        // +128 rows in global

  const int xsl = ((l16 >> 1) & 3);
  const int rofA = (quad ^ xsl) * 8;        // elem offset of this lane's slot

  // prologue: tile 0, all four halves, full drain once
  gld16(gA,           sA + sOff);        gld16(gA + rs,       sA + sOff + 4096);
  gld16(gB,           sB + sOff);        gld16(gB + rs,       sB + sOff + 4096);
  gld16(gA + 32,      sA + HALF + sOff); gld16(gA + 32 + rs,  sA + HALF + sOff + 4096);
  gld16(gB + 32,      sB + HALF + sOff); gld16(gB + 32 + rs,  sB + HALF + sOff + 4096);
  asm volatile("s_waitcnt vmcnt(0)" ::: "memory");
  __builtin_amdgcn_s_barrier();
  __builtin_amdgcn_sched_barrier(0);

  const int nt = K >> 6;
  int p = 0;
  for (int t = 0; t < nt; ++t, p ^= 1) {
    const bf16* aT = sA + p * (2 * HALF);
    const bf16* bT = sB + p * (2 * HALF);
    bf16* aN = sA + (p ^ 1) * (2 * HALF);
    bf16* bN = sB + (p ^ 1) * (2 * HALF);
    const bool pf = (t + 1 < nt);
    const size_t g0 = (size_t)(t + 1) * 64;

    bf16x8 af[8], bfr[4];
    // ---------------- phase 0: ks=0, in 0..1; stage A-k0(t+1) ----------------
#pragma unroll
    for (int im = 0; im < 8; im++)
      af[im] = *(const bf16x8*)&aT[(wm + im * 16 + l16) * 32 + rofA];
    bfr[0] = *(const bf16x8*)&bT[(wn +  0 + l16) * 32 + rofA];
    bfr[1] = *(const bf16x8*)&bT[(wn + 16 + l16) * 32 + rofA];
    if (pf) { gld16(gA + g0, aN + sOff); gld16(gA + g0 + rs, aN + sOff + 4096); }
    __builtin_amdgcn_s_setprio(1);
#pragma unroll
    for (int im = 0; im < 8; im++) {
      acc[im][0] = MFMA16(af[im], bfr[0], acc[im][0]);
      acc[im][1] = MFMA16(af[im], bfr[1], acc[im][1]);
    }
    __builtin_amdgcn_s_setprio(0);
    // ---------------- phase 1: ks=0, in 2..3; stage B-k0(t+1) ----------------
    bfr[2] = *(const bf16x8*)&bT[(wn + 32 + l16) * 32 + rofA];
    bfr[3] = *(const bf16x8*)&bT[(wn + 48 + l16) * 32 + rofA];
    if (pf) { gld16(gB + g0, bN + sOff); gld16(gB + g0 + rs, bN + sOff + 4096); }
    __builtin_amdgcn_s_setprio(1);
#pragma unroll
    for (int im = 0; im < 8; im++) {
      acc[im][2] = MFMA16(af[im], bfr[2], acc[im][2]);
      acc[im][3] = MFMA16(af[im], bfr[3], acc[im][3]);
    }
    __builtin_amdgcn_s_setprio(0);
    asm volatile("s_waitcnt vmcnt(4)" ::: "memory");
    __builtin_amdgcn_s_barrier();
    __builtin_amdgcn_sched_barrier(0);
    // ---------------- phase 2: ks=1, in 0..1; stage A-k1(t+1) ----------------
#pragma unroll
    for (int im = 0; im < 8; im++)
      af[im] = *(const bf16x8*)&aT[HALF + (wm + im * 16 + l16) * 32 + rofA];
    bfr[0] = *(const bf16x8*)&bT[HALF + (wn +  0 + l16) * 32 + rofA];
    bfr[1] = *(const bf16x8*)&bT[HALF + (wn + 16 + l16) * 32 + rofA];
    if (pf) { gld16(gA + g0 + 32, aN + HALF + sOff);
              gld16(gA + g0 + 32 + rs, aN + HALF + sOff + 4096); }
    __builtin_amdgcn_s_setprio(1);
#pragma unroll
    for (int im = 0; im < 8; im++) {
      acc[im][0] = MFMA16(af[im], bfr[0], acc[im][0]);
      acc[im][1] = MFMA16(af[im], bfr[1], acc[im][1]);
    }
    __builtin_amdgcn_s_setprio(0);
    // ---------------- phase 3: ks=1, in 2..3; stage B-k1(t+1) ----------------
    bfr[2] = *(const bf16x8*)&bT[HALF + (wn + 32 + l16) * 32 + rofA];
    bfr[3] = *(const bf16x8*)&bT[HALF + (wn + 48 + l16) * 32 + rofA];
    if (pf) { gld16(gB + g0 + 32, bN + HALF + sOff);
              gld16(gB + g0 + 32 + rs, bN + HALF + sOff + 4096); }
    __builtin_amdgcn_s_setprio(1);
#pragma unroll
    for (int im = 0; im < 8; im++) {
      acc[im][2] = MFMA16(af[im], bfr[2], acc[im][2]);
      acc[im][3] = MFMA16(af[im], bfr[3], acc[im][3]);
    }
    __builtin_amdgcn_s_setprio(0);
    asm volatile("s_waitcnt vmcnt(4)" ::: "memory");
    __builtin_amdgcn_s_barrier();
    __builtin_amdgcn_sched_barrier(0);
  }
}

// ---------------------------------------------------------------------------
// QKV GEMM (256x256 tiles) with fused epilogues (R5 mapping):
//   sel 0 (q): RoPE + scale*log2e fold; sel 1 (k): RoPE; sel 2 (v): transpose.
// ---------------------------------------------------------------------------
__global__ __launch_bounds__(512, 2) void qkv_gemm(const bf16* __restrict__ X,
                                                   const bf16* __restrict__ Wq,
                                                   const bf16* __restrict__ Wk,
                                                   const bf16* __restrict__ Wv,
                                                   bf16* __restrict__ q,
                                                   bf16* __restrict__ kk,
                                                   bf16* __restrict__ vt,
                                                   const float2* __restrict__ tbl) {
  __shared__ bf16 lds[65536];              // 128 KB
  const int sel = blockIdx.x >> 3;
  const int n0 = (blockIdx.x & 7) * 256;
  const int m0 = blockIdx.y * 256;
  const bf16* Bt = (sel == 0) ? Wq : (sel == 1) ? Wk : Wv;

  f32x4 acc[8][4] = {};
  gemm_core256(X, Bt, m0, n0, Cn, acc, lds, lds + 32768);

  const int tid  = threadIdx.x;
  const int lane = tid & 63, wid = tid >> 6;
  const int quad = lane >> 4, l16 = lane & 15;
  const int wm = (wid >> 2) * 128, wn = (wid & 3) * 64;

  if (sel < 2) {
    // ---- RoPE epilogue: pair (2i,2i+1) is adjacent cols -> lane^1 ----
    bf16* out = (sel == 0) ? q : kk;
    const float mscale =
        (sel == 0) ? (0.08838834764831845f * 1.4426950408889634f) : 1.0f;
#pragma unroll
    for (int im = 0; im < 8; im++)
#pragma unroll
      for (int in = 0; in < 4; in++) {
        const int col = n0 + wn + in * 16 + l16;
        const int fi  = (col & 127) >> 1;
        const bool even = ((col & 1) == 0);
#pragma unroll
        for (int r = 0; r < 4; r++) {
          const int row = m0 + wm + im * 16 + quad * 4 + r;
          const int t   = row & (Tn - 1);
          const float xv = acc[im][in][r];
          const float xp = __shfl_xor(xv, 1);
          const float2 cs = tbl[(size_t)t * 64 + fi];
          const float o = even ? (xv * cs.x - xp * cs.y)
                               : (xv * cs.x + xp * cs.y);
          out[(size_t)row * Cn + col] = (bf16)(o * mscale);
        }
      }
  } else {
    // ---- V transpose epilogue: two 128-col halves through LDS ----
    bf16* tr = lds;                         // 256 x 136 = 69.6 KB (<=128 KB)
    const int b  = m0 >> 11;                // 256 | 2048 -> tile never spans b
    const int t0 = m0 & (Tn - 1);
#pragma unroll
    for (int h = 0; h < 2; h++) {
      __syncthreads();
      if (((wid >> 1) & 1) == h) {          // waves whose wn lies in this half
        const int cb = (wid & 1) * 64;
#pragma unroll
        for (int im = 0; im < 8; im++)
#pragma unroll
          for (int in = 0; in < 4; in++)
#pragma unroll
            for (int r = 0; r < 4; r++)
              tr[(wm + im * 16 + quad * 4 + r) * 136 + cb + in * 16 + l16] =
                  (bf16)acc[im][in][r];
      }
      __syncthreads();
      bf16* dst = vt + ((size_t)(b * Cn + n0 + h * 128)) * Tn + t0;
#pragma unroll
      for (int j = 0; j < 8; j++) {
        const int lin = j * 512 + tid;      // 128 c-rows x 32 t-octets
        const int c  = lin >> 5;
        const int t8 = (lin & 31) * 8;
        bf16x8 o;
#pragma unroll
        for (int e = 0; e < 8; e++) o[e] = tr[(t8 + e) * 136 + c];
        *(bf16x8*)(dst + (size_t)c * Tn + t8) = o;
      }
    }
  }
}

// ---------------------------------------------------------------------------
// Output projection GEMM (256x256 tiles, f32 out). R5 mapping.
// ---------------------------------------------------------------------------
__global__ __launch_bounds__(512, 2) void out_gemm(const bf16* __restrict__ Y,
                                                   const bf16* __restrict__ Wp,
                                                   float* __restrict__ O) {
  __shared__ bf16 lds[65536];
  const int m0 = blockIdx.y * 256, n0 = blockIdx.x * 256;

  f32x4 acc[8][4] = {};
  gemm_core256(Y, Wp, m0, n0, Cn, acc, lds, lds + 32768);

  const int tid  = threadIdx.x;
  const int lane = tid & 63, wid = tid >> 6;
  const int quad = lane >> 4, l16 = lane & 15;
  const int wm = (wid >> 2) * 128, wn = (wid & 3) * 64;
#pragma unroll
  for (int im = 0; im < 8; im++)
#pragma unroll
    for (int in = 0; in < 4; in++)
#pragma unroll
      for (int r = 0; r < 4; r++) {
        const int row = m0 + wm + im * 16 + quad * 4 + r;
        const int col = n0 + wn + in * 16 + l16;
        O[(size_t)row * Cn + col] = acc[im][in][r];
      }
}

// ---------------------------------------------------------------------------
// Causal flash attention -- R5 structure restored verbatim (R9's register
// staging spilled: WRITE_SIZE 107->415 MB; abandoned). R10 change: shrink
// sVt/sP strides 72->68 so LDS = 52224 B (was 54272) -> 3 blocks/CU instead
// of 2 (the 160 KB line is at 53.3 KB/block). +50% cross-block TLP for the
// latency-bound stage->barrier->compute chain. Bank check at stride 68
// (136 B = 34 words = +2 mod 32): PV fragment reads 2 lanes/bank (free,
// m136); staging-write starts spread over 16 banks (was 8). VGPR cap at
// launch_bounds(256,3) = 170 >> measured 112: no spill risk.
//   (1) T13 defer-max: skip O/l rescale unless __any(mx > mrow+8).
//   (2) row-sum via MFMA with constant ones B-operand (lacc).
// ---------------------------------------------------------------------------
__global__ __launch_bounds__(256, 3) void attn(const bf16* __restrict__ q,
                                               const bf16* __restrict__ k,
                                               const bf16* __restrict__ vt,
                                               bf16* __restrict__ y) {
  __shared__ bf16 sK[64 * 136];    // K tile (64 keys x 128 d), stride 136
  __shared__ bf16 sVt[128 * 68];   // V^T tile (128 d x 64 keys), stride 68
  __shared__ bf16 sP[128 * 68];    // P tile (128 q x 64 keys), stride 68

  const int tid = threadIdx.x;
  const int bh = blockIdx.x;
  const int qt = 15 - blockIdx.y;          // heavy blocks first
  const int b = bh >> 4, h = bh & 15;
  const int q0 = qt * 128;
  const int lane = tid & 63, w = tid >> 6;
  const int quad = lane >> 4, l16 = lane & 15;

  const bf16* qbase  = q + ((size_t)(b * Tn + q0)) * Cn + h * HD;
  const bf16* kbase  = k + ((size_t)(b * Tn)) * Cn + h * HD;
  const bf16* vtbase = vt + ((size_t)(b * Cn + h * HD)) * Tn;

  bf16x8 qf[2][4];
#pragma unroll
  for (int im = 0; im < 2; im++)
#pragma unroll
    for (int s = 0; s < 4; s++)
      qf[im][s] = *(const bf16x8*)(qbase +
          (size_t)(w * 32 + im * 16 + l16) * Cn + s * 32 + quad * 8);

  f32x4 O[2][8] = {};
  f32x4 lacc[2] = {};
  float mrow[2][4];
#pragma unroll
  for (int im = 0; im < 2; im++)
#pragma unroll
    for (int r = 0; r < 4; r++) mrow[im][r] = -1e30f;

  const bf16x8 vone = {(bf16)1.f, (bf16)1.f, (bf16)1.f, (bf16)1.f,
                       (bf16)1.f, (bf16)1.f, (bf16)1.f, (bf16)1.f};

  const int nkt = 2 * qt + 2;
  for (int kt = 0; kt < nkt; kt++) {
#pragma unroll
    for (int i = 0; i < 4; i++) {            // stage K tile
      int lin = i * 256 + tid;
      int row = lin >> 4, c8 = (lin & 15) * 8;
      *(uint4*)&sK[row * 136 + c8] =
          *(const uint4*)(kbase + (size_t)(kt * 64 + row) * Cn + c8);
    }
#pragma unroll
    for (int i = 0; i < 4; i++) {            // stage V^T tile
      int lin = i * 256 + tid;
      int drow = lin >> 3, k8 = (lin & 7) * 8;
      *(uint4*)&sVt[drow * 68 + k8] =
          *(const uint4*)(vtbase + (size_t)drow * Tn + kt * 64 + k8);
    }
    __syncthreads();

    if (kt * 64 <= q0 + w * 32 + 31) {
      f32x4 sv[2][4] = {};
      __builtin_amdgcn_s_setprio(1);
#pragma unroll
      for (int s = 0; s < 4; s++)
#pragma unroll
        for (int jn = 0; jn < 4; jn++) {
          bf16x8 kf = *(const bf16x8*)&sK[(jn * 16 + l16) * 136 + s * 32 + quad * 8];
          sv[0][jn] = MFMA16(qf[0][s], kf, sv[0][jn]);
          sv[1][jn] = MFMA16(qf[1][s], kf, sv[1][jn]);
        }
      __builtin_amdgcn_s_setprio(0);

      const bool anymask = (kt >= 2 * qt);
#pragma unroll
      for (int im = 0; im < 2; im++)
#pragma unroll
        for (int r = 0; r < 4; r++) {
          float pv[4];
          float mx = -1e30f;
#pragma unroll
          for (int jn = 0; jn < 4; jn++) {
            float x = sv[im][jn][r];
            if (anymask) {
              int key = kt * 64 + jn * 16 + l16;
              int qr  = q0 + w * 32 + im * 16 + quad * 4 + r;
              if (key > qr) x = -1e30f;
            }
            pv[jn] = x;
            mx = fmaxf(mx, x);
          }
          mx = fmaxf(mx, __shfl_xor(mx, 1));
          mx = fmaxf(mx, __shfl_xor(mx, 2));
          mx = fmaxf(mx, __shfl_xor(mx, 4));
          mx = fmaxf(mx, __shfl_xor(mx, 8));
          // T13 defer-max: rescale only when some row grew past mrow + 8
          if (__any(mx > mrow[im][r] + 8.0f)) {
            const float mn = fmaxf(mrow[im][r], mx);
            const float alpha = exp2f(mrow[im][r] - mn);
            mrow[im][r] = mn;
#pragma unroll
            for (int n = 0; n < 8; n++) O[im][n][r] *= alpha;
            lacc[im][r] *= alpha;
          }
          const float mref = mrow[im][r];
#pragma unroll
          for (int jn = 0; jn < 4; jn++) {
            float e = exp2f(pv[jn] - mref);
            sP[(w * 32 + im * 16 + quad * 4 + r) * 68 + jn * 16 + l16] = (bf16)e;
          }
        }

      __builtin_amdgcn_s_setprio(1);
#pragma unroll
      for (int s2 = 0; s2 < 2; s2++) {
        bf16x8 pf0 = *(const bf16x8*)&sP[(w * 32 + l16) * 68 + s2 * 32 + quad * 8];
        bf16x8 pf1 = *(const bf16x8*)&sP[(w * 32 + 16 + l16) * 68 + s2 * 32 + quad * 8];
#pragma unroll
        for (int n = 0; n < 8; n++) {
          bf16x8 vf = *(const bf16x8*)&sVt[(n * 16 + l16) * 68 + s2 * 32 + quad * 8];
          O[0][n] = MFMA16(pf0, vf, O[0][n]);
          O[1][n] = MFMA16(pf1, vf, O[1][n]);
        }
        lacc[0] = MFMA16(pf0, vone, lacc[0]);   // row-sum l += P . 1
        lacc[1] = MFMA16(pf1, vone, lacc[1]);
      }
      __builtin_amdgcn_s_setprio(0);
    }
    __syncthreads();
  }

#pragma unroll
  for (int im = 0; im < 2; im++) {
    bf16* ybase = y + ((size_t)(b * Tn + q0 + w * 32 + im * 16)) * Cn + h * HD;
#pragma unroll
    for (int r = 0; r < 4; r++) {
      const float inv = 1.f / lacc[im][r];
#pragma unroll
      for (int n = 0; n < 8; n++)
        ybase[(size_t)(quad * 4 + r) * Cn + n * 16 + l16] = (bf16)(O[im][n][r] * inv);
    }
  }
}

// ---------------------------------------------------------------------------
// Workspace layout (bf16 elems):
//   [0,TEN)       q          (B*T, C)   roped+scaled
//   [TEN,2TEN)    k          (B*T, C)   roped
//   [2TEN,3TEN)   vt         (B, C, T)
//   [3TEN,4TEN)   xb | y     (xb dead after qkv_gemm; y written by attn)
//   [4TEN,5TEN)   wqb wkb wvb wpb (TEN/4 each, contiguous)
//   [5TEN, +1MB)  rope table (float2, 2048x64)
// ---------------------------------------------------------------------------
extern "C" void kernel_launch(void* const* d_in, const int* in_sizes, int n_in,
                              void* d_out, int out_size, void* d_ws, size_t ws_size,
                              hipStream_t stream) {
  (void)in_sizes; (void)n_in; (void)out_size; (void)ws_size;
  const float* x  = (const float*)d_in[0];
  const float* Wq = (const float*)d_in[1];
  const float* Wk = (const float*)d_in[2];
  const float* Wv = (const float*)d_in[3];
  const float* Wp = (const float*)d_in[4];
  float* out = (float*)d_out;
  bf16*  ws  = (bf16*)d_ws;

  bf16* q   = ws;
  bf16* kk  = ws + TEN;
  bf16* vt  = ws + 2 * TEN;
  bf16* y   = ws + 3 * TEN;
  bf16* xb  = ws + 3 * TEN;          // alias y (dead after qkv_gemm)
  bf16* wqb = ws + 4 * TEN;
  bf16* wkb = ws + 4 * TEN + TEN / 4;
  bf16* wvb = ws + 4 * TEN + TEN / 2;
  bf16* wpb = ws + 4 * TEN + 3 * (TEN / 4);
  float2* tbl = (float2*)(ws + 5 * TEN);

  rope_table <<<dim3(512),  256, 0, stream>>>(tbl);
  to_bf16    <<<dim3(8192), 256, 0, stream>>>(x, xb);
  to_bf16_w4 <<<dim3(2048, 4), 256, 0, stream>>>(Wq, Wk, Wv, Wp, wqb);
  qkv_gemm   <<<dim3(24, 32), 512, 0, stream>>>(xb, wqb, wkb, wvb, q, kk, vt, tbl);
  attn       <<<dim3(64, 16), 256, 0, stream>>>(q, kk, vt, y);
  out_gemm   <<<dim3(8, 32), 512, 0, stream>>>(y, wpb, out);
}

// Round 12
// 604.539 us; speedup vs baseline: 1.1668x; 1.1435x over previous
//
#include <hip/hip_runtime.h>
#include <stdint.h>

typedef __bf16 bf16;
typedef __bf16 bf16x8 __attribute__((ext_vector_type(8)));
typedef float  f32x4  __attribute__((ext_vector_type(4)));

#define MFMA16(a, b, c) __builtin_amdgcn_mfma_f32_16x16x32_bf16((a), (b), (c), 0, 0, 0)

static constexpr int    Bn = 4, Tn = 2048, Cn = 2048, HD = 128;
static constexpr size_t TEN = (size_t)Bn * Tn * Cn;   // 16,777,216 elems

__device__ __forceinline__ void gld16(const void* g, void* l) {
  __builtin_amdgcn_global_load_lds(
      (const __attribute__((address_space(1))) void*)g,
      (__attribute__((address_space(3))) void*)l, 16, 0, 0);
}

// ---------------------------------------------------------------------------
// f32 -> bf16 conversion, 8 elems/thread (x tensor)
// ---------------------------------------------------------------------------
__global__ __launch_bounds__(256) void to_bf16(const float* __restrict__ src,
                                               bf16* __restrict__ dst) {
  const size_t i = ((size_t)blockIdx.x * 256 + threadIdx.x) * 8;
  float4 a = *(const float4*)(src + i);
  float4 b = *(const float4*)(src + i + 4);
  bf16x8 o = {(bf16)a.x, (bf16)a.y, (bf16)a.z, (bf16)a.w,
              (bf16)b.x, (bf16)b.y, (bf16)b.z, (bf16)b.w};
  *(bf16x8*)(dst + i) = o;
}

// ---------------------------------------------------------------------------
// All four weight matrices in ONE launch (blockIdx.y selects source);
// dst regions are contiguous (TEN/4 each).
// ---------------------------------------------------------------------------
__global__ __launch_bounds__(256) void to_bf16_w4(const float* __restrict__ w0,
                                                  const float* __restrict__ w1,
                                                  const float* __restrict__ w2,
                                                  const float* __restrict__ w3,
                                                  bf16* __restrict__ dst) {
  const int s = blockIdx.y;
  const float* src = (s == 0) ? w0 : (s == 1) ? w1 : (s == 2) ? w2 : w3;
  bf16* d = dst + (size_t)s * (TEN / 4);
  const size_t i = ((size_t)blockIdx.x * 256 + threadIdx.x) * 8;
  float4 a = *(const float4*)(src + i);
  float4 b = *(const float4*)(src + i + 4);
  bf16x8 o = {(bf16)a.x, (bf16)a.y, (bf16)a.z, (bf16)a.w,
              (bf16)b.x, (bf16)b.y, (bf16)b.z, (bf16)b.w};
  *(bf16x8*)(d + i) = o;
}

// ---------------------------------------------------------------------------
// RoPE cos/sin table: tbl[t*64 + i] = {cos(t*f_i), sin(t*f_i)}, 2048x64.
// ---------------------------------------------------------------------------
__global__ __launch_bounds__(256) void rope_table(float2* __restrict__ tbl) {
  const int idx = blockIdx.x * 256 + threadIdx.x;   // 512 blocks -> 131072
  const int t = idx >> 6, i = idx & 63;
  const float ang = (float)t * __expf(-(float)i * 0.14391156831212787f); // ln(1e4)/64
  float s, c;
  sincosf(ang, &s, &c);
  tbl[idx] = make_float2(c, s);
}

// ---------------------------------------------------------------------------
// Pipelined 256x256 GEMM core -- R5 version (measured 254.5-257.0 us; FROZEN.
// R8's barrier sandwich: 269 us; R6's XCD remap: FETCH +18 MB, flat dur --
// both reverted. The 4-phase core is a sharp local optimum; do not morph).
// BK=64, 512 threads (8 waves = 2M x 4N), per-wave C = 128x64.
// LDS: 2 dbuf x (A,B) x [2 K-halves][256][32] = 128 KB. 4 phases per K-tile;
// counted vmcnt(4) + raw s_barrier at end of ph1/ph3 only.
//
// T2 LDS swizzle: physical 16B slot = logical ^ ((row>>1)&3); applied via
// pre-swizzled global source slot ((tid&3)^((tid>>3)&3)) + XOR'd read addr
// (quad ^ ((l16>>1)&3)). Verified R3: fragment reads conflict-free.
//
// Wait ledger (per thread, 2 gld16 per phase):
//   stage order iter t: ph0 A-k0(t+1), ph1 B-k0(t+1), ph2 A-k1(t+1), ph3 B-k1(t+1)
//   end-ph3 wait vmcnt(4): outstanding allowed = {A-k1,B-k1}(t+1);
//     guarantees {A-k0,B-k0}(t+1) landed -> read at iter t+1 ph0/ph1.  OK
//   end-ph1 (iter t+1) wait vmcnt(4): outstanding = {A-k0,B-k0}(t+2);
//     guarantees {A-k1,B-k1}(t+1) landed -> read at iter t+1 ph2/ph3.  OK
//   Buffer reuse: writes for tile t+2 (buf p) are issued only after the
//     end-ph3 barrier of iter t, by which point all reads of tile t (buf p)
//     have completed.                                                   OK
// ---------------------------------------------------------------------------
__device__ __forceinline__ void gemm_core256(const bf16* __restrict__ A,
                                             const bf16* __restrict__ Bt,
                                             int m0, int n0, int K,
                                             f32x4 (&acc)[8][4],
                                             bf16* sA, bf16* sB) {
  const int tid  = threadIdx.x;
  const int lane = tid & 63, wid = tid >> 6;
  const int quad = lane >> 4, l16 = lane & 15;
  const int wm = (wid >> 2) * 128, wn = (wid & 3) * 64;

  const int srow = tid >> 2;
  const int scol = ((tid & 3) ^ ((tid >> 3) & 3)) * 8;   // T2 pre-swizzled source
  const bf16* gA = A + (size_t)(m0 + srow) * K + scol;
  const bf16* gB = Bt + (size_t)(n0 + srow) * K + scol;
  const int HALF = 8192;                    // elems per K-half (256 x 32)
  const int sOff = srow * 32 + (tid & 3) * 8;            // linear LDS dest
  const size_t rs = (size_t)128 * K;        // +128 rows in global

  const int xsl = ((l16 >> 1) & 3);
  const int rofA = (quad ^ xsl) * 8;        // elem offset of this lane's slot

  // prologue: tile 0, all four halves, full drain once
  gld16(gA,           sA + sOff);        gld16(gA + rs,       sA + sOff + 4096);
  gld16(gB,           sB + sOff);        gld16(gB + rs,       sB + sOff + 4096);
  gld16(gA + 32,      sA + HALF + sOff); gld16(gA + 32 + rs,  sA + HALF + sOff + 4096);
  gld16(gB + 32,      sB + HALF + sOff); gld16(gB + 32 + rs,  sB + HALF + sOff + 4096);
  asm volatile("s_waitcnt vmcnt(0)" ::: "memory");
  __builtin_amdgcn_s_barrier();
  __builtin_amdgcn_sched_barrier(0);

  const int nt = K >> 6;
  int p = 0;
  for (int t = 0; t < nt; ++t, p ^= 1) {
    const bf16* aT = sA + p * (2 * HALF);
    const bf16* bT = sB + p * (2 * HALF);
    bf16* aN = sA + (p ^ 1) * (2 * HALF);
    bf16* bN = sB + (p ^ 1) * (2 * HALF);
    const bool pf = (t + 1 < nt);
    const size_t g0 = (size_t)(t + 1) * 64;

    bf16x8 af[8], bfr[4];
    // ---------------- phase 0: ks=0, in 0..1; stage A-k0(t+1) ----------------
#pragma unroll
    for (int im = 0; im < 8; im++)
      af[im] = *(const bf16x8*)&aT[(wm + im * 16 + l16) * 32 + rofA];
    bfr[0] = *(const bf16x8*)&bT[(wn +  0 + l16) * 32 + rofA];
    bfr[1] = *(const bf16x8*)&bT[(wn + 16 + l16) * 32 + rofA];
    if (pf) { gld16(gA + g0, aN + sOff); gld16(gA + g0 + rs, aN + sOff + 4096); }
    __builtin_amdgcn_s_setprio(1);
#pragma unroll
    for (int im = 0; im < 8; im++) {
      acc[im][0] = MFMA16(af[im], bfr[0], acc[im][0]);
      acc[im][1] = MFMA16(af[im], bfr[1], acc[im][1]);
    }
    __builtin_amdgcn_s_setprio(0);
    // ---------------- phase 1: ks=0, in 2..3; stage B-k0(t+1) ----------------
    bfr[2] = *(const bf16x8*)&bT[(wn + 32 + l16) * 32 + rofA];
    bfr[3] = *(const bf16x8*)&bT[(wn + 48 + l16) * 32 + rofA];
    if (pf) { gld16(gB + g0, bN + sOff); gld16(gB + g0 + rs, bN + sOff + 4096); }
    __builtin_amdgcn_s_setprio(1);
#pragma unroll
    for (int im = 0; im < 8; im++) {
      acc[im][2] = MFMA16(af[im], bfr[2], acc[im][2]);
      acc[im][3] = MFMA16(af[im], bfr[3], acc[im][3]);
    }
    __builtin_amdgcn_s_setprio(0);
    asm volatile("s_waitcnt vmcnt(4)" ::: "memory");
    __builtin_amdgcn_s_barrier();
    __builtin_amdgcn_sched_barrier(0);
    // ---------------- phase 2: ks=1, in 0..1; stage A-k1(t+1) ----------------
#pragma unroll
    for (int im = 0; im < 8; im++)
      af[im] = *(const bf16x8*)&aT[HALF + (wm + im * 16 + l16) * 32 + rofA];
    bfr[0] = *(const bf16x8*)&bT[HALF + (wn +  0 + l16) * 32 + rofA];
    bfr[1] = *(const bf16x8*)&bT[HALF + (wn + 16 + l16) * 32 + rofA];
    if (pf) { gld16(gA + g0 + 32, aN + HALF + sOff);
              gld16(gA + g0 + 32 + rs, aN + HALF + sOff + 4096); }
    __builtin_amdgcn_s_setprio(1);
#pragma unroll
    for (int im = 0; im < 8; im++) {
      acc[im][0] = MFMA16(af[im], bfr[0], acc[im][0]);
      acc[im][1] = MFMA16(af[im], bfr[1], acc[im][1]);
    }
    __builtin_amdgcn_s_setprio(0);
    // ---------------- phase 3: ks=1, in 2..3; stage B-k1(t+1) ----------------
    bfr[2] = *(const bf16x8*)&bT[HALF + (wn + 32 + l16) * 32 + rofA];
    bfr[3] = *(const bf16x8*)&bT[HALF + (wn + 48 + l16) * 32 + rofA];
    if (pf) { gld16(gB + g0 + 32, bN + HALF + sOff);
              gld16(gB + g0 + 32 + rs, bN + HALF + sOff + 4096); }
    __builtin_amdgcn_s_setprio(1);
#pragma unroll
    for (int im = 0; im < 8; im++) {
      acc[im][2] = MFMA16(af[im], bfr[2], acc[im][2]);
      acc[im][3] = MFMA16(af[im], bfr[3], acc[im][3]);
    }
    __builtin_amdgcn_s_setprio(0);
    asm volatile("s_waitcnt vmcnt(4)" ::: "memory");
    __builtin_amdgcn_s_barrier();
    __builtin_amdgcn_sched_barrier(0);
  }
}

// ---------------------------------------------------------------------------
// QKV GEMM (256x256 tiles) with fused epilogues (R5 mapping):
//   sel 0 (q): RoPE + scale*log2e fold; sel 1 (k): RoPE; sel 2 (v): transpose.
// ---------------------------------------------------------------------------
__global__ __launch_bounds__(512, 2) void qkv_gemm(const bf16* __restrict__ X,
                                                   const bf16* __restrict__ Wq,
                                                   const bf16* __restrict__ Wk,
                                                   const bf16* __restrict__ Wv,
                                                   bf16* __restrict__ q,
                                                   bf16* __restrict__ kk,
                                                   bf16* __restrict__ vt,
                                                   const float2* __restrict__ tbl) {
  __shared__ bf16 lds[65536];              // 128 KB
  const int sel = blockIdx.x >> 3;
  const int n0 = (blockIdx.x & 7) * 256;
  const int m0 = blockIdx.y * 256;
  const bf16* Bt = (sel == 0) ? Wq : (sel == 1) ? Wk : Wv;

  f32x4 acc[8][4] = {};
  gemm_core256(X, Bt, m0, n0, Cn, acc, lds, lds + 32768);

  const int tid  = threadIdx.x;
  const int lane = tid & 63, wid = tid >> 6;
  const int quad = lane >> 4, l16 = lane & 15;
  const int wm = (wid >> 2) * 128, wn = (wid & 3) * 64;

  if (sel < 2) {
    // ---- RoPE epilogue: pair (2i,2i+1) is adjacent cols -> lane^1 ----
    bf16* out = (sel == 0) ? q : kk;
    const float mscale =
        (sel == 0) ? (0.08838834764831845f * 1.4426950408889634f) : 1.0f;
#pragma unroll
    for (int im = 0; im < 8; im++)
#pragma unroll
      for (int in = 0; in < 4; in++) {
        const int col = n0 + wn + in * 16 + l16;
        const int fi  = (col & 127) >> 1;
        const bool even = ((col & 1) == 0);
#pragma unroll
        for (int r = 0; r < 4; r++) {
          const int row = m0 + wm + im * 16 + quad * 4 + r;
          const int t   = row & (Tn - 1);
          const float xv = acc[im][in][r];
          const float xp = __shfl_xor(xv, 1);
          const float2 cs = tbl[(size_t)t * 64 + fi];
          const float o = even ? (xv * cs.x - xp * cs.y)
                               : (xv * cs.x + xp * cs.y);
          out[(size_t)row * Cn + col] = (bf16)(o * mscale);
        }
      }
  } else {
    // ---- V transpose epilogue: two 128-col halves through LDS ----
    bf16* tr = lds;                         // 256 x 136 = 69.6 KB (<=128 KB)
    const int b  = m0 >> 11;                // 256 | 2048 -> tile never spans b
    const int t0 = m0 & (Tn - 1);
#pragma unroll
    for (int h = 0; h < 2; h++) {
      __syncthreads();
      if (((wid >> 1) & 1) == h) {          // waves whose wn lies in this half
        const int cb = (wid & 1) * 64;
#pragma unroll
        for (int im = 0; im < 8; im++)
#pragma unroll
          for (int in = 0; in < 4; in++)
#pragma unroll
            for (int r = 0; r < 4; r++)
              tr[(wm + im * 16 + quad * 4 + r) * 136 + cb + in * 16 + l16] =
                  (bf16)acc[im][in][r];
      }
      __syncthreads();
      bf16* dst = vt + ((size_t)(b * Cn + n0 + h * 128)) * Tn + t0;
#pragma unroll
      for (int j = 0; j < 8; j++) {
        const int lin = j * 512 + tid;      // 128 c-rows x 32 t-octets
        const int c  = lin >> 5;
        const int t8 = (lin & 31) * 8;
        bf16x8 o;
#pragma unroll
        for (int e = 0; e < 8; e++) o[e] = tr[(t8 + e) * 136 + c];
        *(bf16x8*)(dst + (size_t)c * Tn + t8) = o;
      }
    }
  }
}

// ---------------------------------------------------------------------------
// Output projection GEMM (256x256 tiles, f32 out). R5 mapping.
// ---------------------------------------------------------------------------
__global__ __launch_bounds__(512, 2) void out_gemm(const bf16* __restrict__ Y,
                                                   const bf16* __restrict__ Wp,
                                                   float* __restrict__ O) {
  __shared__ bf16 lds[65536];
  const int m0 = blockIdx.y * 256, n0 = blockIdx.x * 256;

  f32x4 acc[8][4] = {};
  gemm_core256(Y, Wp, m0, n0, Cn, acc, lds, lds + 32768);

  const int tid  = threadIdx.x;
  const int lane = tid & 63, wid = tid >> 6;
  const int quad = lane >> 4, l16 = lane & 15;
  const int wm = (wid >> 2) * 128, wn = (wid & 3) * 64;
#pragma unroll
  for (int im = 0; im < 8; im++)
#pragma unroll
    for (int in = 0; in < 4; in++)
#pragma unroll
      for (int r = 0; r < 4; r++) {
        const int row = m0 + wm + im * 16 + quad * 4 + r;
        const int col = n0 + wn + in * 16 + l16;
        O[(size_t)row * Cn + col] = acc[im][in][r];
      }
}

// ---------------------------------------------------------------------------
// Causal flash attention -- R5 version EXACT (best measured; ~220 us).
// Strides 136/72/72 are bank-optimal (dword stride ≡ 4 mod 32 spreads the
// wave's b128 reads over all 32 banks at the 8-access minimum; R11's
// stride-68 ≡ 2 mod 32 hit even banks only and regressed ~+80 us).
// launch_bounds(256,2): 2 blocks/CU. R9's register staging spilled
// (WRITE_SIZE 107->415 MB); R7's max-free softmax regressed; both abandoned.
//   (1) T13 defer-max: skip O/l rescale unless __any(mx > mrow+8).
//   (2) row-sum via MFMA with constant ones B-operand (lacc).
// ---------------------------------------------------------------------------
__global__ __launch_bounds__(256, 2) void attn(const bf16* __restrict__ q,
                                               const bf16* __restrict__ k,
                                               const bf16* __restrict__ vt,
                                               bf16* __restrict__ y) {
  __shared__ bf16 sK[64 * 136];    // K tile (64 keys x 128 d), stride 136
  __shared__ bf16 sVt[128 * 72];   // V^T tile (128 d x 64 keys), stride 72
  __shared__ bf16 sP[128 * 72];    // P tile (128 q x 64 keys), stride 72

  const int tid = threadIdx.x;
  const int bh = blockIdx.x;
  const int qt = 15 - blockIdx.y;          // heavy blocks first
  const int b = bh >> 4, h = bh & 15;
  const int q0 = qt * 128;
  const int lane = tid & 63, w = tid >> 6;
  const int quad = lane >> 4, l16 = lane & 15;

  const bf16* qbase  = q + ((size_t)(b * Tn + q0)) * Cn + h * HD;
  const bf16* kbase  = k + ((size_t)(b * Tn)) * Cn + h * HD;
  const bf16* vtbase = vt + ((size_t)(b * Cn + h * HD)) * Tn;

  bf16x8 qf[2][4];
#pragma unroll
  for (int im = 0; im < 2; im++)
#pragma unroll
    for (int s = 0; s < 4; s++)
      qf[im][s] = *(const bf16x8*)(qbase +
          (size_t)(w * 32 + im * 16 + l16) * Cn + s * 32 + quad * 8);

  f32x4 O[2][8] = {};
  f32x4 lacc[2] = {};
  float mrow[2][4];
#pragma unroll
  for (int im = 0; im < 2; im++)
#pragma unroll
    for (int r = 0; r < 4; r++) mrow[im][r] = -1e30f;

  const bf16x8 vone = {(bf16)1.f, (bf16)1.f, (bf16)1.f, (bf16)1.f,
                       (bf16)1.f, (bf16)1.f, (bf16)1.f, (bf16)1.f};

  const int nkt = 2 * qt + 2;
  for (int kt = 0; kt < nkt; kt++) {
#pragma unroll
    for (int i = 0; i < 4; i++) {            // stage K tile
      int lin = i * 256 + tid;
      int row = lin >> 4, c8 = (lin & 15) * 8;
      *(uint4*)&sK[row * 136 + c8] =
          *(const uint4*)(kbase + (size_t)(kt * 64 + row) * Cn + c8);
    }
#pragma unroll
    for (int i = 0; i < 4; i++) {            // stage V^T tile
      int lin = i * 256 + tid;
      int drow = lin >> 3, k8 = (lin & 7) * 8;
      *(uint4*)&sVt[drow * 72 + k8] =
          *(const uint4*)(vtbase + (size_t)drow * Tn + kt * 64 + k8);
    }
    __syncthreads();

    if (kt * 64 <= q0 + w * 32 + 31) {
      f32x4 sv[2][4] = {};
      __builtin_amdgcn_s_setprio(1);
#pragma unroll
      for (int s = 0; s < 4; s++)
#pragma unroll
        for (int jn = 0; jn < 4; jn++) {
          bf16x8 kf = *(const bf16x8*)&sK[(jn * 16 + l16) * 136 + s * 32 + quad * 8];
          sv[0][jn] = MFMA16(qf[0][s], kf, sv[0][jn]);
          sv[1][jn] = MFMA16(qf[1][s], kf, sv[1][jn]);
        }
      __builtin_amdgcn_s_setprio(0);

      const bool anymask = (kt >= 2 * qt);
#pragma unroll
      for (int im = 0; im < 2; im++)
#pragma unroll
        for (int r = 0; r < 4; r++) {
          float pv[4];
          float mx = -1e30f;
#pragma unroll
          for (int jn = 0; jn < 4; jn++) {
            float x = sv[im][jn][r];
            if (anymask) {
              int key = kt * 64 + jn * 16 + l16;
              int qr  = q0 + w * 32 + im * 16 + quad * 4 + r;
              if (key > qr) x = -1e30f;
            }
            pv[jn] = x;
            mx = fmaxf(mx, x);
          }
          mx = fmaxf(mx, __shfl_xor(mx, 1));
          mx = fmaxf(mx, __shfl_xor(mx, 2));
          mx = fmaxf(mx, __shfl_xor(mx, 4));
          mx = fmaxf(mx, __shfl_xor(mx, 8));
          // T13 defer-max: rescale only when some row grew past mrow + 8
          if (__any(mx > mrow[im][r] + 8.0f)) {
            const float mn = fmaxf(mrow[im][r], mx);
            const float alpha = exp2f(mrow[im][r] - mn);
            mrow[im][r] = mn;
#pragma unroll
            for (int n = 0; n < 8; n++) O[im][n][r] *= alpha;
            lacc[im][r] *= alpha;
          }
          const float mref = mrow[im][r];
#pragma unroll
          for (int jn = 0; jn < 4; jn++) {
            float e = exp2f(pv[jn] - mref);
            sP[(w * 32 + im * 16 + quad * 4 + r) * 72 + jn * 16 + l16] = (bf16)e;
          }
        }

      __builtin_amdgcn_s_setprio(1);
#pragma unroll
      for (int s2 = 0; s2 < 2; s2++) {
        bf16x8 pf0 = *(const bf16x8*)&sP[(w * 32 + l16) * 72 + s2 * 32 + quad * 8];
        bf16x8 pf1 = *(const bf16x8*)&sP[(w * 32 + 16 + l16) * 72 + s2 * 32 + quad * 8];
#pragma unroll
        for (int n = 0; n < 8; n++) {
          bf16x8 vf = *(const bf16x8*)&sVt[(n * 16 + l16) * 72 + s2 * 32 + quad * 8];
          O[0][n] = MFMA16(pf0, vf, O[0][n]);
          O[1][n] = MFMA16(pf1, vf, O[1][n]);
        }
        lacc[0] = MFMA16(pf0, vone, lacc[0]);   // row-sum l += P . 1
        lacc[1] = MFMA16(pf1, vone, lacc[1]);
      }
      __builtin_amdgcn_s_setprio(0);
    }
    __syncthreads();
  }

#pragma unroll
  for (int im = 0; im < 2; im++) {
    bf16* ybase = y + ((size_t)(b * Tn + q0 + w * 32 + im * 16)) * Cn + h * HD;
#pragma unroll
    for (int r = 0; r < 4; r++) {
      const float inv = 1.f / lacc[im][r];
#pragma unroll
      for (int n = 0; n < 8; n++)
        ybase[(size_t)(quad * 4 + r) * Cn + n * 16 + l16] = (bf16)(O[im][n][r] * inv);
    }
  }
}

// ---------------------------------------------------------------------------
// Workspace layout (bf16 elems):
//   [0,TEN)       q          (B*T, C)   roped+scaled
//   [TEN,2TEN)    k          (B*T, C)   roped
//   [2TEN,3TEN)   vt         (B, C, T)
//   [3TEN,4TEN)   xb | y     (xb dead after qkv_gemm; y written by attn)
//   [4TEN,5TEN)   wqb wkb wvb wpb (TEN/4 each, contiguous)
//   [5TEN, +1MB)  rope table (float2, 2048x64)
// ---------------------------------------------------------------------------
extern "C" void kernel_launch(void* const* d_in, const int* in_sizes, int n_in,
                              void* d_out, int out_size, void* d_ws, size_t ws_size,
                              hipStream_t stream) {
  (void)in_sizes; (void)n_in; (void)out_size; (void)ws_size;
  const float* x  = (const float*)d_in[0];
  const float* Wq = (const float*)d_in[1];
  const float* Wk = (const float*)d_in[2];
  const float* Wv = (const float*)d_in[3];
  const float* Wp = (const float*)d_in[4];
  float* out = (float*)d_out;
  bf16*  ws  = (bf16*)d_ws;

  bf16* q   = ws;
  bf16* kk  = ws + TEN;
  bf16* vt  = ws + 2 * TEN;
  bf16* y   = ws + 3 * TEN;
  bf16* xb  = ws + 3 * TEN;          // alias y (dead after qkv_gemm)
  bf16* wqb = ws + 4 * TEN;
  bf16* wkb = ws + 4 * TEN + TEN / 4;
  bf16* wvb = ws + 4 * TEN + TEN / 2;
  bf16* wpb = ws + 4 * TEN + 3 * (TEN / 4);
  float2* tbl = (float2*)(ws + 5 * TEN);

  rope_table <<<dim3(512),  256, 0, stream>>>(tbl);
  to_bf16    <<<dim3(8192), 256, 0, stream>>>(x, xb);
  to_bf16_w4 <<<dim3(2048, 4), 256, 0, stream>>>(Wq, Wk, Wv, Wp, wqb);
  qkv_gemm   <<<dim3(24, 32), 512, 0, stream>>>(xb, wqb, wkb, wvb, q, kk, vt, tbl);
  attn       <<<dim3(64, 16), 256, 0, stream>>>(q, kk, vt, y);
  out_gemm   <<<dim3(8, 32), 512, 0, stream>>>(y, wpb, out);
}